// Round 9
// baseline (491.397 us; speedup 1.0000x reference)
//
#include <hip/hip_runtime.h>
#include <math.h>

// GAT 3-layer: N=50000 nodes, E=800000 edges (+N self loops), HEADS=2, HID=64.
// R9: (1) gemm restructured 64x64 block (grid y = head), 4x4 micro-tile:
// W slice K x 64 is L1-resident; per-wave W traffic /4 (R8 audit: gemms were
// L2-BW-bound streaming W, ~150us of the 482). (2) aggregate gather pipelined
// 2-deep ping-pong (16 loads in flight vs 8).

__device__ __forceinline__ float lrelu(float v) { return v > 0.f ? v : 0.2f * v; }

__device__ __forceinline__ float wave_sum(float v) {
  for (int off = 32; off; off >>= 1) v += __shfl_xor(v, off, 64);
  return v;
}
__device__ __forceinline__ float wave_max(float v) {
  for (int off = 32; off; off >>= 1) v = fmaxf(v, __shfl_xor(v, off, 64));
  return v;
}

__global__ void init_kernel(int* __restrict__ deg, float* __restrict__ gsum,
                            int* __restrict__ gcnt, int n, int g) {
  int i = blockIdx.x * blockDim.x + threadIdx.x;
  if (i < n) deg[i] = 1;                 // self loop
  if (i < g) { gsum[i] = 0.f; gcnt[i] = 0; }
}

__global__ void count_kernel(const int* __restrict__ ei, int* __restrict__ deg, int e) {
  int i = blockIdx.x * blockDim.x + threadIdx.x;
  if (i < e) atomicAdd(&deg[ei[e + i]], 1);   // dst row of edge_index
}

// ---- hierarchical exclusive scan over deg[0..n) ----
__global__ void scan_blocks(const int* __restrict__ deg, int* __restrict__ row_ptr,
                            int* __restrict__ btot, int n) {
  __shared__ int sm[256];
  int i = blockIdx.x * 256 + threadIdx.x;
  int v = (i < n) ? deg[i] : 0;
  sm[threadIdx.x] = v;
  __syncthreads();
  for (int off = 1; off < 256; off <<= 1) {
    int t = (threadIdx.x >= off) ? sm[threadIdx.x - off] : 0;
    __syncthreads();
    sm[threadIdx.x] += t;
    __syncthreads();
  }
  if (i < n) row_ptr[i] = sm[threadIdx.x] - v;   // exclusive within block
  if (threadIdx.x == 255) btot[blockIdx.x] = sm[255];
}

__global__ void scan_totals(int* __restrict__ btot, int nb) {  // nb <= 256
  __shared__ int sm[256];
  int v = (threadIdx.x < nb) ? btot[threadIdx.x] : 0;
  sm[threadIdx.x] = v;
  __syncthreads();
  for (int off = 1; off < 256; off <<= 1) {
    int t = (threadIdx.x >= off) ? sm[threadIdx.x - off] : 0;
    __syncthreads();
    sm[threadIdx.x] += t;
    __syncthreads();
  }
  if (threadIdx.x < nb) btot[threadIdx.x] = sm[threadIdx.x] - v;  // exclusive
}

__global__ void scan_add(int* __restrict__ row_ptr, int* __restrict__ cursor,
                         const int* __restrict__ btot, int n, int total) {
  int i = blockIdx.x * 256 + threadIdx.x;
  if (i < n) {
    int v = row_ptr[i] + btot[blockIdx.x];
    row_ptr[i] = v;
    cursor[i] = v;
  }
  if (i == 0) row_ptr[n] = total;
}

__global__ void scatter_kernel(const int* __restrict__ ei, int* __restrict__ cursor,
                               int* __restrict__ csr_src, int n, int e) {
  int i = blockIdx.x * blockDim.x + threadIdx.x;
  if (i < n) {                               // self loop
    int p = atomicAdd(&cursor[i], 1);
    csr_src[p] = i;
  } else if (i < n + e) {
    int j = i - n;
    int s = ei[j];
    int d = ei[e + j];
    int p = atomicAdd(&cursor[d], 1);
    csr_src[p] = s;
  }
}

// Tiled gemm + fused attention reduce.
// Block = 64 rows x 64 cols (blockIdx.y = head). 256 threads: cgrp = tid&15
// -> cols head*64 + cgrp*4; rg = tid>>4 -> rows rg*4..+4. 4x4 acc/thread.
// X tile in LDS (pad K+1; 4 rg-addresses/wave, 516 floats apart -> distinct
// banks). W slice Kx64 = 16-32KB: L1-resident, 256B/wave/k (was 1KB).
// Att reduce over cgrp via 16-lane shfl_xor.
template <int K>
__global__ __launch_bounds__(256) void gemm_att(const float* __restrict__ X,
                                                const float* __restrict__ W,
                                                const float* __restrict__ asw,
                                                const float* __restrict__ adw,
                                                float* __restrict__ H,
                                                float* __restrict__ a_src,
                                                float* __restrict__ a_dst, int N) {
  __shared__ float Xs[64 * (K + 1)];
  int tid = threadIdx.x;
  int row0 = blockIdx.x * 64;
  int head = blockIdx.y;

  for (int idx = tid; idx < 64 * K; idx += 256) {
    int r = idx / K;
    int k = idx - r * K;
    int gr = row0 + r;
    if (gr >= N) gr = N - 1;          // clamp pad rows (stores are guarded)
    Xs[r * (K + 1) + k] = X[(size_t)gr * K + k];
  }
  __syncthreads();

  int cgrp = tid & 15;
  int rg = tid >> 4;
  int c0 = head * 64 + cgrp * 4;
  const float* wp = W + c0;
  float acc[4][4] = {};

#pragma unroll 4
  for (int k = 0; k < K; ++k) {
    float4 w4 = *(const float4*)(wp + k * 128);
#pragma unroll
    for (int j = 0; j < 4; ++j) {
      float xv = Xs[(rg * 4 + j) * (K + 1) + k];
      acc[j][0] = fmaf(xv, w4.x, acc[j][0]);
      acc[j][1] = fmaf(xv, w4.y, acc[j][1]);
      acc[j][2] = fmaf(xv, w4.z, acc[j][2]);
      acc[j][3] = fmaf(xv, w4.w, acc[j][3]);
    }
  }

  float4 aw = *(const float4*)(asw + c0);
  float4 dw = *(const float4*)(adw + c0);
#pragma unroll
  for (int j = 0; j < 4; ++j) {
    int r = row0 + rg * 4 + j;
    float sp = acc[j][0] * aw.x + acc[j][1] * aw.y + acc[j][2] * aw.z + acc[j][3] * aw.w;
    float dp = acc[j][0] * dw.x + acc[j][1] * dw.y + acc[j][2] * dw.z + acc[j][3] * dw.w;
#pragma unroll
    for (int off = 1; off < 16; off <<= 1) {
      sp += __shfl_xor(sp, off, 64);
      dp += __shfl_xor(dp, off, 64);
    }
    if (r < N) {
      float4 v = make_float4(acc[j][0], acc[j][1], acc[j][2], acc[j][3]);
      *(float4*)(H + (size_t)r * 128 + c0) = v;
      if (cgrp == 0) {
        a_src[r * 2 + head] = sp;
        a_dst[r * 2 + head] = dp;
      }
    }
  }
}

// ---- pipelined gather helpers: groups of 8 edges; idx<=63 always; tail
// slots carry s=0, p=0 (row 0 stays L1-hot, fma adds 0) ----
__device__ __forceinline__ void ld_grp(const float* __restrict__ H, int lane,
                                       bool hi, int s, float p0, float p1, int g,
                                       float2* h, float* q) {
#pragma unroll
  for (int k = 0; k < 8; ++k) {
    int idx = g * 8 + k;
    int st = __shfl(s, idx, 64);
    float q0 = __shfl(p0, idx, 64);
    float q1 = __shfl(p1, idx, 64);
    q[k] = hi ? q1 : q0;
    h[k] = *(const float2*)(H + (size_t)st * 128 + (lane << 1));
  }
}
__device__ __forceinline__ void fma_grp(const float2* h, const float* q,
                                        float& ax, float& ay) {
#pragma unroll
  for (int k = 0; k < 8; ++k) {
    ax = fmaf(h[k].x, q[k], ax);
    ay = fmaf(h[k].y, q[k], ay);
  }
}
__device__ __forceinline__ void gather_pipe(const float* __restrict__ H, int lane,
                                            bool hi, int s, float p0, float p1,
                                            int cnt, float& ax, float& ay) {
  int groups = (cnt + 7) >> 3;   // 1..8
  float2 ha[8], hb[8];
  float qa[8], qb[8];
  ld_grp(H, lane, hi, s, p0, p1, 0, ha, qa);
  int g = 1;
  for (; g + 1 < groups; g += 2) {
    ld_grp(H, lane, hi, s, p0, p1, g, hb, qb);
    fma_grp(ha, qa, ax, ay);
    ld_grp(H, lane, hi, s, p0, p1, g + 1, ha, qa);
    fma_grp(hb, qb, ax, ay);
  }
  if (g < groups) {
    ld_grp(H, lane, hi, s, p0, p1, g, hb, qb);
    fma_grp(ha, qa, ax, ay);
    fma_grp(hb, qb, ax, ay);
  } else {
    fma_grp(ha, qa, ax, ay);
  }
}

// Fused softmax + aggregate. Wave per dst node.
__global__ __launch_bounds__(256) void aggregate_fused(
    const float* __restrict__ H, const float* __restrict__ a_src,
    const float* __restrict__ a_dst, const float* __restrict__ bias,
    const int* __restrict__ row_ptr, const int* __restrict__ csr,
    float* __restrict__ out, int N) {
  int wid = blockIdx.x * (blockDim.x >> 6) + (threadIdx.x >> 6);
  if (wid >= N) return;
  int lane = threadIdx.x & 63;
  bool hi = lane >= 32;
  int beg = row_ptr[wid], end = row_ptr[wid + 1];
  float2 ad = ((const float2*)a_dst)[wid];
  float ax = 0.f, ay = 0.f;
  float inv0, inv1;

  if (end - beg <= 64) {
    // ---- fast path: single chunk ----
    int j = beg + lane;
    bool valid = j < end;
    int s = valid ? csr[j] : 0;
    float2 as = ((const float2*)a_src)[s];
    float e0 = valid ? lrelu(as.x + ad.x) : -1e30f;
    float e1 = valid ? lrelu(as.y + ad.y) : -1e30f;
    float m0 = wave_max(e0);
    float m1 = wave_max(e1);
    float p0 = __expf(e0 - m0);   // 0 for invalid lanes
    float p1 = __expf(e1 - m1);
    inv0 = 1.f / fmaxf(wave_sum(valid ? p0 : 0.f), 1e-16f);
    inv1 = 1.f / fmaxf(wave_sum(valid ? p1 : 0.f), 1e-16f);
    gather_pipe(H, lane, hi, s, p0, p1, end - beg, ax, ay);
  } else {
    // ---- generic path: online softmax across 64-edge chunks ----
    float m0 = -1e30f, m1 = -1e30f, s0 = 0.f, s1 = 0.f;
    for (int base = beg; base < end; base += 64) {
      int j = base + lane;
      bool valid = j < end;
      int s = valid ? csr[j] : 0;
      float2 as = ((const float2*)a_src)[s];
      float e0 = valid ? lrelu(as.x + ad.x) : -1e30f;
      float e1 = valid ? lrelu(as.y + ad.y) : -1e30f;
      float nm0 = fmaxf(m0, wave_max(e0));
      float nm1 = fmaxf(m1, wave_max(e1));
      s0 = s0 * __expf(m0 - nm0) + wave_sum(valid ? __expf(e0 - nm0) : 0.f);
      s1 = s1 * __expf(m1 - nm1) + wave_sum(valid ? __expf(e1 - nm1) : 0.f);
      m0 = nm0; m1 = nm1;
    }
    inv0 = 1.f / fmaxf(s0, 1e-16f);
    inv1 = 1.f / fmaxf(s1, 1e-16f);
    for (int base = beg; base < end; base += 64) {
      int j = base + lane;
      bool valid = j < end;
      int s = valid ? csr[j] : 0;
      float2 as = ((const float2*)a_src)[s];
      float e0 = valid ? lrelu(as.x + ad.x) : -1e30f;
      float e1 = valid ? lrelu(as.y + ad.y) : -1e30f;
      float p0 = __expf(e0 - m0);
      float p1 = __expf(e1 - m1);
      int cnt = end - base;
      if (cnt > 64) cnt = 64;
      gather_pipe(H, lane, hi, s, p0, p1, cnt, ax, ay);
    }
  }

  float il = hi ? inv1 : inv0;
  ax *= il;
  ay *= il;
  float ox = 0.5f * (ax + __shfl_xor(ax, 32, 64));
  float oy = 0.5f * (ay + __shfl_xor(ay, 32, 64));
  if (lane < 32) {
    int c = lane * 2;
    float v0 = ox + bias[c];
    float v1 = oy + bias[c + 1];
    v0 = v0 > 0.f ? v0 : 0.f;
    v1 = v1 > 0.f ? v1 : 0.f;
    *(float2*)(out + (size_t)wid * 64 + c) = make_float2(v0, v1);
  }
}

// per-node dot with lin_w (linear commutes past the mean), atomic per-graph
__global__ void pool_kernel(const float* __restrict__ X, const float* __restrict__ lw,
                            const int* __restrict__ batch, float* __restrict__ gsum,
                            int* __restrict__ gcnt, int N) {
  int wid = blockIdx.x * (blockDim.x >> 6) + (threadIdx.x >> 6);
  if (wid >= N) return;
  int lane = threadIdx.x & 63;
  float v = X[(size_t)wid * 64 + lane] * lw[lane];
  v = wave_sum(v);
  if (lane == 0) {
    int g = batch[wid];
    atomicAdd(&gsum[g], v);
    atomicAdd(&gcnt[g], 1);
  }
}

__global__ void finalize_kernel(const float* __restrict__ gsum, const int* __restrict__ gcnt,
                                const float* __restrict__ lb, float* __restrict__ out, int G) {
  int g = blockIdx.x * blockDim.x + threadIdx.x;
  if (g < G) out[g] = gsum[g] / fmaxf((float)gcnt[g], 1.f) + lb[0];
}

extern "C" void kernel_launch(void* const* d_in, const int* in_sizes, int n_in,
                              void* d_out, int out_size, void* d_ws, size_t ws_size,
                              hipStream_t stream) {
  const float* x   = (const float*)d_in[0];
  const int* ei    = (const int*)d_in[1];
  const int* batch = (const int*)d_in[2];
  const float* W1  = (const float*)d_in[3];
  const float* as1 = (const float*)d_in[4];
  const float* ad1 = (const float*)d_in[5];
  const float* b1  = (const float*)d_in[6];
  const float* W2  = (const float*)d_in[7];
  const float* as2 = (const float*)d_in[8];
  const float* ad2 = (const float*)d_in[9];
  const float* b2  = (const float*)d_in[10];
  const float* W3  = (const float*)d_in[11];
  const float* as3 = (const float*)d_in[12];
  const float* ad3 = (const float*)d_in[13];
  const float* b3  = (const float*)d_in[14];
  const float* lw  = (const float*)d_in[15];
  const float* lb  = (const float*)d_in[16];
  float* out = (float*)d_out;

  const int N = in_sizes[0] / 128;   // 50000
  const int E = in_sizes[1] / 2;     // 800000
  const int ET = N + E;              // with self loops
  const int G = out_size;            // 2500
  const int NB = (N + 255) / 256;    // scan blocks (196 <= 256)

  char* p = (char*)d_ws;
  auto take = [&](size_t bytes) {
    char* r = p;
    p += (bytes + 255) & ~(size_t)255;
    return r;
  };
  int* deg      = (int*)take((size_t)N * 4);
  int* row_ptr  = (int*)take((size_t)(N + 1) * 4);
  int* cursor   = (int*)take((size_t)N * 4);
  int* btot     = (int*)take((size_t)NB * 4);
  int* csr      = (int*)take((size_t)ET * 4);
  float* H      = (float*)take((size_t)N * 128 * 4);
  float* a_src  = (float*)take((size_t)N * 2 * 4);
  float* a_dst  = (float*)take((size_t)N * 2 * 4);
  float* bufA   = (float*)take((size_t)N * 64 * 4);
  float* bufB   = (float*)take((size_t)N * 64 * 4);
  float* gsum   = (float*)take((size_t)G * 4);
  int* gcnt     = (int*)take((size_t)G * 4);
  (void)ws_size; (void)n_in;

  // ---- CSR build (dst-sorted, with self loops) ----
  init_kernel<<<(N + 255) / 256, 256, 0, stream>>>(deg, gsum, gcnt, N, G);
  count_kernel<<<(E + 255) / 256, 256, 0, stream>>>(ei, deg, E);
  scan_blocks<<<NB, 256, 0, stream>>>(deg, row_ptr, btot, N);
  scan_totals<<<1, 256, 0, stream>>>(btot, NB);
  scan_add<<<NB, 256, 0, stream>>>(row_ptr, cursor, btot, N, ET);
  scatter_kernel<<<(ET + 255) / 256, 256, 0, stream>>>(ei, cursor, csr, N, E);

  const dim3 gblk((N + 63) / 64, 2);
  const int wblk = (N + 3) / 4;

  // ---- layer 1 (K=128) ----
  gemm_att<128><<<gblk, 256, 0, stream>>>(x, W1, as1, ad1, H, a_src, a_dst, N);
  aggregate_fused<<<wblk, 256, 0, stream>>>(H, a_src, a_dst, b1, row_ptr, csr, bufA, N);
  // ---- layer 2 (K=64) ----
  gemm_att<64><<<gblk, 256, 0, stream>>>(bufA, W2, as2, ad2, H, a_src, a_dst, N);
  aggregate_fused<<<wblk, 256, 0, stream>>>(H, a_src, a_dst, b2, row_ptr, csr, bufB, N);
  // ---- layer 3 (K=64) ----
  gemm_att<64><<<gblk, 256, 0, stream>>>(bufB, W3, as3, ad3, H, a_src, a_dst, N);
  aggregate_fused<<<wblk, 256, 0, stream>>>(H, a_src, a_dst, b3, row_ptr, csr, bufA, N);

  // ---- pool + linear ----
  pool_kernel<<<wblk, 256, 0, stream>>>(bufA, lw, batch, gsum, gcnt, N);
  finalize_kernel<<<(G + 255) / 256, 256, 0, stream>>>(gsum, gcnt, lb, out, G);
}

// Round 10
// 439.267 us; speedup vs baseline: 1.1187x; 1.1187x over previous
//
#include <hip/hip_runtime.h>
#include <math.h>

// GAT 3-layer: N=50000 nodes, E=800000 edges (+N self loops), HEADS=2, HID=64.
// R10: CSR build without the atomic->random-store chain (R9 showed scatter =
// 62us, atomic-return latency bound): count_rank stores the atomic's return
// coalesced; place writes csr with NO atomics (4 indep edges/thread). Self
// loop = rank 0, placed in scan_add. Pool fused into layer-3 aggregate;
// gcnt counted in scan_add.

__device__ __forceinline__ float lrelu(float v) { return v > 0.f ? v : 0.2f * v; }

__device__ __forceinline__ float wave_sum(float v) {
  for (int off = 32; off; off >>= 1) v += __shfl_xor(v, off, 64);
  return v;
}
__device__ __forceinline__ float wave_max(float v) {
  for (int off = 32; off; off >>= 1) v = fmaxf(v, __shfl_xor(v, off, 64));
  return v;
}

__global__ void init_kernel(int* __restrict__ deg, float* __restrict__ gsum,
                            int* __restrict__ gcnt, int n, int g) {
  int i = blockIdx.x * blockDim.x + threadIdx.x;
  if (i < n) deg[i] = 1;                 // self loop occupies rank 0
  if (i < g) { gsum[i] = 0.f; gcnt[i] = 0; }
}

// rank[j] = arrival order of edge j within its dst (starts at 1; 0 = self loop)
__global__ void count_rank(const int* __restrict__ ei, int* __restrict__ deg,
                           int* __restrict__ rank, int e) {
  int j = blockIdx.x * blockDim.x + threadIdx.x;
  if (j < e) rank[j] = atomicAdd(&deg[ei[e + j]], 1);
}

// ---- hierarchical exclusive scan over deg[0..n) ----
__global__ void scan_blocks(const int* __restrict__ deg, int* __restrict__ row_ptr,
                            int* __restrict__ btot, int n) {
  __shared__ int sm[256];
  int i = blockIdx.x * 256 + threadIdx.x;
  int v = (i < n) ? deg[i] : 0;
  sm[threadIdx.x] = v;
  __syncthreads();
  for (int off = 1; off < 256; off <<= 1) {
    int t = (threadIdx.x >= off) ? sm[threadIdx.x - off] : 0;
    __syncthreads();
    sm[threadIdx.x] += t;
    __syncthreads();
  }
  if (i < n) row_ptr[i] = sm[threadIdx.x] - v;   // exclusive within block
  if (threadIdx.x == 255) btot[blockIdx.x] = sm[255];
}

__global__ void scan_totals(int* __restrict__ btot, int nb) {  // nb <= 256
  __shared__ int sm[256];
  int v = (threadIdx.x < nb) ? btot[threadIdx.x] : 0;
  sm[threadIdx.x] = v;
  __syncthreads();
  for (int off = 1; off < 256; off <<= 1) {
    int t = (threadIdx.x >= off) ? sm[threadIdx.x - off] : 0;
    __syncthreads();
    sm[threadIdx.x] += t;
    __syncthreads();
  }
  if (threadIdx.x < nb) btot[threadIdx.x] = sm[threadIdx.x] - v;  // exclusive
}

// finalize row_ptr, drop self-loop into csr (rank 0), count nodes per graph
__global__ void scan_add(int* __restrict__ row_ptr, int* __restrict__ csr,
                         const int* __restrict__ btot, const int* __restrict__ batch,
                         int* __restrict__ gcnt, int n, int total) {
  int i = blockIdx.x * 256 + threadIdx.x;
  if (i < n) {
    int v = row_ptr[i] + btot[blockIdx.x];
    row_ptr[i] = v;
    csr[v] = i;                         // self loop
    atomicAdd(&gcnt[batch[i]], 1);
  }
  if (i == 0) row_ptr[n] = total;
}

// no atomics: slot = row_ptr[dst] + rank. 4 independent edges per thread
// (coalesced ei/rank loads, L2-hot row_ptr read, fire-and-forget store).
__global__ void place_kernel(const int* __restrict__ ei, const int* __restrict__ rank,
                             const int* __restrict__ row_ptr, int* __restrict__ csr,
                             int e) {
  int j0 = blockIdx.x * (blockDim.x * 4) + threadIdx.x;
#pragma unroll
  for (int k = 0; k < 4; ++k) {
    int j = j0 + k * 256;
    if (j < e) {
      int d = ei[e + j];
      csr[row_ptr[d] + rank[j]] = ei[j];
    }
  }
}

// Tiled gemm + fused attention reduce.
// Block = 64 rows x 64 cols (blockIdx.y = head). 256 threads: cgrp = tid&15
// -> cols head*64 + cgrp*4; rg = tid>>4 -> rows rg*4..+4. 4x4 acc/thread.
// W slice Kx64 L1-resident. Att reduce over cgrp via 16-lane shfl_xor.
template <int K>
__global__ __launch_bounds__(256) void gemm_att(const float* __restrict__ X,
                                                const float* __restrict__ W,
                                                const float* __restrict__ asw,
                                                const float* __restrict__ adw,
                                                float* __restrict__ H,
                                                float* __restrict__ a_src,
                                                float* __restrict__ a_dst, int N) {
  __shared__ float Xs[64 * (K + 1)];
  int tid = threadIdx.x;
  int row0 = blockIdx.x * 64;
  int head = blockIdx.y;

  for (int idx = tid; idx < 64 * K; idx += 256) {
    int r = idx / K;
    int k = idx - r * K;
    int gr = row0 + r;
    if (gr >= N) gr = N - 1;          // clamp pad rows (stores are guarded)
    Xs[r * (K + 1) + k] = X[(size_t)gr * K + k];
  }
  __syncthreads();

  int cgrp = tid & 15;
  int rg = tid >> 4;
  int c0 = head * 64 + cgrp * 4;
  const float* wp = W + c0;
  float acc[4][4] = {};

#pragma unroll 4
  for (int k = 0; k < K; ++k) {
    float4 w4 = *(const float4*)(wp + k * 128);
#pragma unroll
    for (int j = 0; j < 4; ++j) {
      float xv = Xs[(rg * 4 + j) * (K + 1) + k];
      acc[j][0] = fmaf(xv, w4.x, acc[j][0]);
      acc[j][1] = fmaf(xv, w4.y, acc[j][1]);
      acc[j][2] = fmaf(xv, w4.z, acc[j][2]);
      acc[j][3] = fmaf(xv, w4.w, acc[j][3]);
    }
  }

  float4 aw = *(const float4*)(asw + c0);
  float4 dw = *(const float4*)(adw + c0);
#pragma unroll
  for (int j = 0; j < 4; ++j) {
    int r = row0 + rg * 4 + j;
    float sp = acc[j][0] * aw.x + acc[j][1] * aw.y + acc[j][2] * aw.z + acc[j][3] * aw.w;
    float dp = acc[j][0] * dw.x + acc[j][1] * dw.y + acc[j][2] * dw.z + acc[j][3] * dw.w;
#pragma unroll
    for (int off = 1; off < 16; off <<= 1) {
      sp += __shfl_xor(sp, off, 64);
      dp += __shfl_xor(dp, off, 64);
    }
    if (r < N) {
      float4 v = make_float4(acc[j][0], acc[j][1], acc[j][2], acc[j][3]);
      *(float4*)(H + (size_t)r * 128 + c0) = v;
      if (cgrp == 0) {
        a_src[r * 2 + head] = sp;
        a_dst[r * 2 + head] = dp;
      }
    }
  }
}

// ---- pipelined gather helpers: groups of 8 edges; idx<=63 always; tail
// slots carry s=0, p=0 (row 0 stays L1-hot, fma adds 0) ----
__device__ __forceinline__ void ld_grp(const float* __restrict__ H, int lane,
                                       bool hi, int s, float p0, float p1, int g,
                                       float2* h, float* q) {
#pragma unroll
  for (int k = 0; k < 8; ++k) {
    int idx = g * 8 + k;
    int st = __shfl(s, idx, 64);
    float q0 = __shfl(p0, idx, 64);
    float q1 = __shfl(p1, idx, 64);
    q[k] = hi ? q1 : q0;
    h[k] = *(const float2*)(H + (size_t)st * 128 + (lane << 1));
  }
}
__device__ __forceinline__ void fma_grp(const float2* h, const float* q,
                                        float& ax, float& ay) {
#pragma unroll
  for (int k = 0; k < 8; ++k) {
    ax = fmaf(h[k].x, q[k], ax);
    ay = fmaf(h[k].y, q[k], ay);
  }
}
__device__ __forceinline__ void gather_pipe(const float* __restrict__ H, int lane,
                                            bool hi, int s, float p0, float p1,
                                            int cnt, float& ax, float& ay) {
  int groups = (cnt + 7) >> 3;   // 1..8
  float2 ha[8], hb[8];
  float qa[8], qb[8];
  ld_grp(H, lane, hi, s, p0, p1, 0, ha, qa);
  int g = 1;
  for (; g + 1 < groups; g += 2) {
    ld_grp(H, lane, hi, s, p0, p1, g, hb, qb);
    fma_grp(ha, qa, ax, ay);
    ld_grp(H, lane, hi, s, p0, p1, g + 1, ha, qa);
    fma_grp(hb, qb, ax, ay);
  }
  if (g < groups) {
    ld_grp(H, lane, hi, s, p0, p1, g, hb, qb);
    fma_grp(ha, qa, ax, ay);
    fma_grp(hb, qb, ax, ay);
  } else {
    fma_grp(ha, qa, ax, ay);
  }
}

// Fused softmax + aggregate. Wave per dst node. POOL=1: fold graph-pool dot
// (out row . lin_w) into the epilogue, one atomicAdd per node; no out store.
template <int POOL>
__global__ __launch_bounds__(256) void aggregate_fused(
    const float* __restrict__ H, const float* __restrict__ a_src,
    const float* __restrict__ a_dst, const float* __restrict__ bias,
    const int* __restrict__ row_ptr, const int* __restrict__ csr,
    float* __restrict__ out, const float* __restrict__ lw,
    const int* __restrict__ batch, float* __restrict__ gsum, int N) {
  int wid = blockIdx.x * (blockDim.x >> 6) + (threadIdx.x >> 6);
  if (wid >= N) return;
  int lane = threadIdx.x & 63;
  bool hi = lane >= 32;
  int beg = row_ptr[wid], end = row_ptr[wid + 1];
  float2 ad = ((const float2*)a_dst)[wid];
  float ax = 0.f, ay = 0.f;
  float inv0, inv1;

  if (end - beg <= 64) {
    // ---- fast path: single chunk ----
    int j = beg + lane;
    bool valid = j < end;
    int s = valid ? csr[j] : 0;
    float2 as = ((const float2*)a_src)[s];
    float e0 = valid ? lrelu(as.x + ad.x) : -1e30f;
    float e1 = valid ? lrelu(as.y + ad.y) : -1e30f;
    float m0 = wave_max(e0);
    float m1 = wave_max(e1);
    float p0 = __expf(e0 - m0);   // 0 for invalid lanes
    float p1 = __expf(e1 - m1);
    inv0 = 1.f / fmaxf(wave_sum(valid ? p0 : 0.f), 1e-16f);
    inv1 = 1.f / fmaxf(wave_sum(valid ? p1 : 0.f), 1e-16f);
    gather_pipe(H, lane, hi, s, p0, p1, end - beg, ax, ay);
  } else {
    // ---- generic path: online softmax across 64-edge chunks ----
    float m0 = -1e30f, m1 = -1e30f, s0 = 0.f, s1 = 0.f;
    for (int base = beg; base < end; base += 64) {
      int j = base + lane;
      bool valid = j < end;
      int s = valid ? csr[j] : 0;
      float2 as = ((const float2*)a_src)[s];
      float e0 = valid ? lrelu(as.x + ad.x) : -1e30f;
      float e1 = valid ? lrelu(as.y + ad.y) : -1e30f;
      float nm0 = fmaxf(m0, wave_max(e0));
      float nm1 = fmaxf(m1, wave_max(e1));
      s0 = s0 * __expf(m0 - nm0) + wave_sum(valid ? __expf(e0 - nm0) : 0.f);
      s1 = s1 * __expf(m1 - nm1) + wave_sum(valid ? __expf(e1 - nm1) : 0.f);
      m0 = nm0; m1 = nm1;
    }
    inv0 = 1.f / fmaxf(s0, 1e-16f);
    inv1 = 1.f / fmaxf(s1, 1e-16f);
    for (int base = beg; base < end; base += 64) {
      int j = base + lane;
      bool valid = j < end;
      int s = valid ? csr[j] : 0;
      float2 as = ((const float2*)a_src)[s];
      float e0 = valid ? lrelu(as.x + ad.x) : -1e30f;
      float e1 = valid ? lrelu(as.y + ad.y) : -1e30f;
      float p0 = __expf(e0 - m0);
      float p1 = __expf(e1 - m1);
      int cnt = end - base;
      if (cnt > 64) cnt = 64;
      gather_pipe(H, lane, hi, s, p0, p1, cnt, ax, ay);
    }
  }

  float il = hi ? inv1 : inv0;
  ax *= il;
  ay *= il;
  float ox = 0.5f * (ax + __shfl_xor(ax, 32, 64));
  float oy = 0.5f * (ay + __shfl_xor(ay, 32, 64));
  int c = lane * 2;
  float v0 = ox + bias[c & 63];
  float v1 = oy + bias[(c & 63) + 1];
  v0 = v0 > 0.f ? v0 : 0.f;
  v1 = v1 > 0.f ? v1 : 0.f;
  if (POOL) {
    float pv = (lane < 32) ? (v0 * lw[c] + v1 * lw[c + 1]) : 0.f;
    pv = wave_sum(pv);
    if (lane == 0) atomicAdd(&gsum[batch[wid]], pv);
  } else if (lane < 32) {
    *(float2*)(out + (size_t)wid * 64 + c) = make_float2(v0, v1);
  }
}

__global__ void finalize_kernel(const float* __restrict__ gsum, const int* __restrict__ gcnt,
                                const float* __restrict__ lb, float* __restrict__ out, int G) {
  int g = blockIdx.x * blockDim.x + threadIdx.x;
  if (g < G) out[g] = gsum[g] / fmaxf((float)gcnt[g], 1.f) + lb[0];
}

extern "C" void kernel_launch(void* const* d_in, const int* in_sizes, int n_in,
                              void* d_out, int out_size, void* d_ws, size_t ws_size,
                              hipStream_t stream) {
  const float* x   = (const float*)d_in[0];
  const int* ei    = (const int*)d_in[1];
  const int* batch = (const int*)d_in[2];
  const float* W1  = (const float*)d_in[3];
  const float* as1 = (const float*)d_in[4];
  const float* ad1 = (const float*)d_in[5];
  const float* b1  = (const float*)d_in[6];
  const float* W2  = (const float*)d_in[7];
  const float* as2 = (const float*)d_in[8];
  const float* ad2 = (const float*)d_in[9];
  const float* b2  = (const float*)d_in[10];
  const float* W3  = (const float*)d_in[11];
  const float* as3 = (const float*)d_in[12];
  const float* ad3 = (const float*)d_in[13];
  const float* b3  = (const float*)d_in[14];
  const float* lw  = (const float*)d_in[15];
  const float* lb  = (const float*)d_in[16];
  float* out = (float*)d_out;

  const int N = in_sizes[0] / 128;   // 50000
  const int E = in_sizes[1] / 2;     // 800000
  const int ET = N + E;              // with self loops
  const int G = out_size;            // 2500
  const int NB = (N + 255) / 256;    // scan blocks (196 <= 256)

  char* p = (char*)d_ws;
  auto take = [&](size_t bytes) {
    char* r = p;
    p += (bytes + 255) & ~(size_t)255;
    return r;
  };
  int* deg      = (int*)take((size_t)N * 4);
  int* row_ptr  = (int*)take((size_t)(N + 1) * 4);
  int* rank     = (int*)take((size_t)E * 4);
  int* btot     = (int*)take((size_t)NB * 4);
  int* csr      = (int*)take((size_t)ET * 4);
  float* H      = (float*)take((size_t)N * 128 * 4);
  float* a_src  = (float*)take((size_t)N * 2 * 4);
  float* a_dst  = (float*)take((size_t)N * 2 * 4);
  float* bufA   = (float*)take((size_t)N * 64 * 4);
  float* bufB   = (float*)take((size_t)N * 64 * 4);
  float* gsum   = (float*)take((size_t)G * 4);
  int* gcnt     = (int*)take((size_t)G * 4);
  (void)ws_size; (void)n_in;

  // ---- CSR build (dst-grouped, with self loops) ----
  init_kernel<<<(N + 255) / 256, 256, 0, stream>>>(deg, gsum, gcnt, N, G);
  count_rank<<<(E + 255) / 256, 256, 0, stream>>>(ei, deg, rank, E);
  scan_blocks<<<NB, 256, 0, stream>>>(deg, row_ptr, btot, N);
  scan_totals<<<1, 256, 0, stream>>>(btot, NB);
  scan_add<<<NB, 256, 0, stream>>>(row_ptr, csr, btot, batch, gcnt, N, ET);
  place_kernel<<<(E + 1023) / 1024, 256, 0, stream>>>(ei, rank, row_ptr, csr, E);

  const dim3 gblk((N + 63) / 64, 2);
  const int wblk = (N + 3) / 4;

  // ---- layer 1 (K=128) ----
  gemm_att<128><<<gblk, 256, 0, stream>>>(x, W1, as1, ad1, H, a_src, a_dst, N);
  aggregate_fused<0><<<wblk, 256, 0, stream>>>(H, a_src, a_dst, b1, row_ptr, csr,
                                               bufA, lw, batch, gsum, N);
  // ---- layer 2 (K=64) ----
  gemm_att<64><<<gblk, 256, 0, stream>>>(bufA, W2, as2, ad2, H, a_src, a_dst, N);
  aggregate_fused<0><<<wblk, 256, 0, stream>>>(H, a_src, a_dst, b2, row_ptr, csr,
                                               bufB, lw, batch, gsum, N);
  // ---- layer 3 (K=64) + fused pool ----
  gemm_att<64><<<gblk, 256, 0, stream>>>(bufB, W3, as3, ad3, H, a_src, a_dst, N);
  aggregate_fused<1><<<wblk, 256, 0, stream>>>(H, a_src, a_dst, b3, row_ptr, csr,
                                               bufA, lw, batch, gsum, N);

  // ---- finalize ----
  finalize_kernel<<<(G + 255) / 256, 256, 0, stream>>>(gsum, gcnt, lb, out, G);
}

// Round 11
// 427.165 us; speedup vs baseline: 1.1504x; 1.0283x over previous
//
#include <hip/hip_runtime.h>
#include <math.h>

// GAT 3-layer: N=50000 nodes, E=800000 edges (+N self loops), HEADS=2, HID=64.
// R11: aggregate reworked to 2 dsts/wave with float4 lanes (32 lanes x 16B =
// full 512B H row per half-wave): 1KB per load instr + 8-deep pipeline =
// 2x bytes in flight vs R10 (which plateaued at 3.4 TB/s). Pool: per-node pv
// plain store + boundary finalize via binary search (R10's gsum atomicAdd on
// 2500 hot addrs cost +15us). count_rank: 4 atomics in flight.

__device__ __forceinline__ float lrelu(float v) { return v > 0.f ? v : 0.2f * v; }

__device__ __forceinline__ float wave_max(float v) {
  for (int off = 32; off; off >>= 1) v = fmaxf(v, __shfl_xor(v, off, 64));
  return v;
}
// 32-lane (half-wave) reductions: xor offsets stay within the half
__device__ __forceinline__ float half_sum(float v) {
  for (int off = 16; off; off >>= 1) v += __shfl_xor(v, off, 64);
  return v;
}
__device__ __forceinline__ float half_max(float v) {
  for (int off = 16; off; off >>= 1) v = fmaxf(v, __shfl_xor(v, off, 64));
  return v;
}

__global__ void init_kernel(int* __restrict__ deg, int n) {
  int i = blockIdx.x * blockDim.x + threadIdx.x;
  if (i < n) deg[i] = 1;                 // self loop occupies rank 0
}

// rank[j] = arrival order within dst (1-based; 0 = self loop). 4 indep atomics.
__global__ void count_rank(const int* __restrict__ ei, int* __restrict__ deg,
                           int* __restrict__ rank, int e) {
  int j0 = blockIdx.x * 1024 + threadIdx.x;
#pragma unroll
  for (int k = 0; k < 4; ++k) {
    int j = j0 + k * 256;
    if (j < e) rank[j] = atomicAdd(&deg[ei[e + j]], 1);
  }
}

// ---- hierarchical exclusive scan over deg[0..n) ----
__global__ void scan_blocks(const int* __restrict__ deg, int* __restrict__ row_ptr,
                            int* __restrict__ btot, int n) {
  __shared__ int sm[256];
  int i = blockIdx.x * 256 + threadIdx.x;
  int v = (i < n) ? deg[i] : 0;
  sm[threadIdx.x] = v;
  __syncthreads();
  for (int off = 1; off < 256; off <<= 1) {
    int t = (threadIdx.x >= off) ? sm[threadIdx.x - off] : 0;
    __syncthreads();
    sm[threadIdx.x] += t;
    __syncthreads();
  }
  if (i < n) row_ptr[i] = sm[threadIdx.x] - v;   // exclusive within block
  if (threadIdx.x == 255) btot[blockIdx.x] = sm[255];
}

__global__ void scan_totals(int* __restrict__ btot, int nb) {  // nb <= 256
  __shared__ int sm[256];
  int v = (threadIdx.x < nb) ? btot[threadIdx.x] : 0;
  sm[threadIdx.x] = v;
  __syncthreads();
  for (int off = 1; off < 256; off <<= 1) {
    int t = (threadIdx.x >= off) ? sm[threadIdx.x - off] : 0;
    __syncthreads();
    sm[threadIdx.x] += t;
    __syncthreads();
  }
  if (threadIdx.x < nb) btot[threadIdx.x] = sm[threadIdx.x] - v;  // exclusive
}

// finalize row_ptr + drop self-loop into csr (rank 0)
__global__ void scan_add(int* __restrict__ row_ptr, int* __restrict__ csr,
                         const int* __restrict__ btot, int n, int total) {
  int i = blockIdx.x * 256 + threadIdx.x;
  if (i < n) {
    int v = row_ptr[i] + btot[blockIdx.x];
    row_ptr[i] = v;
    csr[v] = i;                         // self loop
  }
  if (i == 0) row_ptr[n] = total;
}

// no atomics: slot = row_ptr[dst] + rank. 4 independent edges per thread.
__global__ void place_kernel(const int* __restrict__ ei, const int* __restrict__ rank,
                             const int* __restrict__ row_ptr, int* __restrict__ csr,
                             int e) {
  int j0 = blockIdx.x * 1024 + threadIdx.x;
#pragma unroll
  for (int k = 0; k < 4; ++k) {
    int j = j0 + k * 256;
    if (j < e) {
      int d = ei[e + j];
      csr[row_ptr[d] + rank[j]] = ei[j];
    }
  }
}

// Tiled gemm + fused attention reduce.
// Block = 64 rows x 64 cols (blockIdx.y = head). 256 threads: cgrp = tid&15
// -> cols head*64 + cgrp*4; rg = tid>>4 -> rows rg*4..+4. 4x4 acc/thread.
// W slice Kx64 L1-resident. Att reduce over cgrp via 16-lane shfl_xor.
template <int K>
__global__ __launch_bounds__(256) void gemm_att(const float* __restrict__ X,
                                                const float* __restrict__ W,
                                                const float* __restrict__ asw,
                                                const float* __restrict__ adw,
                                                float* __restrict__ H,
                                                float* __restrict__ a_src,
                                                float* __restrict__ a_dst, int N) {
  __shared__ float Xs[64 * (K + 1)];
  int tid = threadIdx.x;
  int row0 = blockIdx.x * 64;
  int head = blockIdx.y;

  for (int idx = tid; idx < 64 * K; idx += 256) {
    int r = idx / K;
    int k = idx - r * K;
    int gr = row0 + r;
    if (gr >= N) gr = N - 1;          // clamp pad rows (stores are guarded)
    Xs[r * (K + 1) + k] = X[(size_t)gr * K + k];
  }
  __syncthreads();

  int cgrp = tid & 15;
  int rg = tid >> 4;
  int c0 = head * 64 + cgrp * 4;
  const float* wp = W + c0;
  float acc[4][4] = {};

#pragma unroll 4
  for (int k = 0; k < K; ++k) {
    float4 w4 = *(const float4*)(wp + k * 128);
#pragma unroll
    for (int j = 0; j < 4; ++j) {
      float xv = Xs[(rg * 4 + j) * (K + 1) + k];
      acc[j][0] = fmaf(xv, w4.x, acc[j][0]);
      acc[j][1] = fmaf(xv, w4.y, acc[j][1]);
      acc[j][2] = fmaf(xv, w4.z, acc[j][2]);
      acc[j][3] = fmaf(xv, w4.w, acc[j][3]);
    }
  }

  float4 aw = *(const float4*)(asw + c0);
  float4 dw = *(const float4*)(adw + c0);
#pragma unroll
  for (int j = 0; j < 4; ++j) {
    int r = row0 + rg * 4 + j;
    float sp = acc[j][0] * aw.x + acc[j][1] * aw.y + acc[j][2] * aw.z + acc[j][3] * aw.w;
    float dp = acc[j][0] * dw.x + acc[j][1] * dw.y + acc[j][2] * dw.z + acc[j][3] * dw.w;
#pragma unroll
    for (int off = 1; off < 16; off <<= 1) {
      sp += __shfl_xor(sp, off, 64);
      dp += __shfl_xor(dp, off, 64);
    }
    if (r < N) {
      float4 v = make_float4(acc[j][0], acc[j][1], acc[j][2], acc[j][3]);
      *(float4*)(H + (size_t)r * 128 + c0) = v;
      if (cgrp == 0) {
        a_src[r * 2 + head] = sp;
        a_dst[r * 2 + head] = dp;
      }
    }
  }
}

// ---- float4 pipelined gather: 8 loads (1KB each) in flight per wave ----
__device__ __forceinline__ void ld_grp4(const float* __restrict__ H, int half,
                                        int col4, int headsel, int s, float p0,
                                        float p1, int g, float4* h, float* q) {
#pragma unroll
  for (int k = 0; k < 8; ++k) {
    int idx = half + g * 8 + k;          // within own half (g*8+k <= 31)
    int st = __shfl(s, idx, 64);
    float q0 = __shfl(p0, idx, 64);
    float q1 = __shfl(p1, idx, 64);
    q[k] = headsel ? q1 : q0;
    h[k] = *(const float4*)(H + (size_t)st * 128 + col4);
  }
}
__device__ __forceinline__ void fma_grp4(const float4* h, const float* q,
                                         float4& a) {
#pragma unroll
  for (int k = 0; k < 8; ++k) {
    a.x = fmaf(h[k].x, q[k], a.x);
    a.y = fmaf(h[k].y, q[k], a.y);
    a.z = fmaf(h[k].z, q[k], a.z);
    a.w = fmaf(h[k].w, q[k], a.w);
  }
}
__device__ __forceinline__ void gather_pipe4(const float* __restrict__ H, int half,
                                             int col4, int headsel, int s, float p0,
                                             float p1, int maxcnt, float4& a) {
  int groups = (maxcnt + 7) >> 3;   // 1..4 (chunk of 32)
  float4 ha[8], hb[8];
  float qa[8], qb[8];
  ld_grp4(H, half, col4, headsel, s, p0, p1, 0, ha, qa);
  int g = 1;
  for (; g + 1 < groups; g += 2) {
    ld_grp4(H, half, col4, headsel, s, p0, p1, g, hb, qb);
    fma_grp4(ha, qa, a);
    ld_grp4(H, half, col4, headsel, s, p0, p1, g + 1, ha, qa);
    fma_grp4(hb, qb, a);
  }
  if (g < groups) {
    ld_grp4(H, half, col4, headsel, s, p0, p1, g, hb, qb);
    fma_grp4(ha, qa, a);
    fma_grp4(hb, qb, a);
  } else {
    fma_grp4(ha, qa, a);
  }
}

// Fused softmax + aggregate. 2 dsts per wave: lanes 0-31 -> dst A, 32-63 ->
// dst B. Lane l covers H cols (l&31)*4..+4 (lanes 0-15 of half = head0 cols,
// 16-31 = head1). Softmax per half (32-lane reduce). POOL=1: per-node pv
// plain store into pvn (no atomics).
template <int POOL>
__global__ __launch_bounds__(256) void aggregate_fused(
    const float* __restrict__ H, const float* __restrict__ a_src,
    const float* __restrict__ a_dst, const float* __restrict__ bias,
    const int* __restrict__ row_ptr, const int* __restrict__ csr,
    float* __restrict__ out, const float* __restrict__ lw,
    float* __restrict__ pvn, int N) {
  int lane = threadIdx.x & 63;
  int half = lane & 32;                 // 0 or 32
  int l32 = lane & 31;
  int dst = blockIdx.x * 8 + ((threadIdx.x >> 6) << 1) + (half >> 5);
  bool live = dst < N;
  int beg = live ? row_ptr[dst] : 0;
  int end = live ? row_ptr[dst + 1] : 0;
  int cnt = end - beg;                  // >= 1 when live (self loop)
  float2 ad = live ? ((const float2*)a_dst)[dst] : make_float2(0.f, 0.f);
  int col4 = l32 * 4;
  int headsel = (l32 >> 4) & 1;         // 0: cols 0-63, 1: cols 64-127
  float4 acc = make_float4(0.f, 0.f, 0.f, 0.f);
  float inv0, inv1;

  // wave-uniform max degree (drives loop counts)
  int maxcnt = (int)wave_max((float)cnt);

  if (maxcnt <= 32) {
    // ---- fast path: single 32-chunk per half ----
    int j = beg + l32;
    bool valid = l32 < cnt;
    int s = valid ? csr[j] : 0;
    float2 as = ((const float2*)a_src)[s];
    float e0 = valid ? lrelu(as.x + ad.x) : -1e30f;
    float e1 = valid ? lrelu(as.y + ad.y) : -1e30f;
    float m0 = half_max(e0);
    float m1 = half_max(e1);
    float p0 = __expf(e0 - m0);         // 0 for invalid lanes
    float p1 = __expf(e1 - m1);
    inv0 = 1.f / fmaxf(half_sum(valid ? p0 : 0.f), 1e-16f);
    inv1 = 1.f / fmaxf(half_sum(valid ? p1 : 0.f), 1e-16f);
    gather_pipe4(H, half, col4, headsel, s, p0, p1, maxcnt, acc);
  } else {
    // ---- generic path: online softmax over 32-edge chunks per half ----
    float m0 = -1e30f, m1 = -1e30f, s0 = 0.f, s1 = 0.f;
    for (int base = 0; base < maxcnt; base += 32) {
      int j = beg + base + l32;
      bool valid = (base + l32) < cnt;
      int s = valid ? csr[j] : 0;
      float2 as = ((const float2*)a_src)[s];
      float e0 = valid ? lrelu(as.x + ad.x) : -1e30f;
      float e1 = valid ? lrelu(as.y + ad.y) : -1e30f;
      float nm0 = fmaxf(m0, half_max(e0));
      float nm1 = fmaxf(m1, half_max(e1));
      s0 = s0 * __expf(m0 - nm0) + half_sum(valid ? __expf(e0 - nm0) : 0.f);
      s1 = s1 * __expf(m1 - nm1) + half_sum(valid ? __expf(e1 - nm1) : 0.f);
      m0 = nm0; m1 = nm1;
    }
    inv0 = 1.f / fmaxf(s0, 1e-16f);
    inv1 = 1.f / fmaxf(s1, 1e-16f);
    for (int base = 0; base < maxcnt; base += 32) {
      int j = beg + base + l32;
      bool valid = (base + l32) < cnt;
      int s = valid ? csr[j] : 0;
      float2 as = ((const float2*)a_src)[s];
      float e0 = valid ? lrelu(as.x + ad.x) : -1e30f;
      float e1 = valid ? lrelu(as.y + ad.y) : -1e30f;
      float p0 = __expf(e0 - m0);       // 0 invalid
      float p1 = __expf(e1 - m1);
      int rem = maxcnt - base;
      if (rem > 32) rem = 32;
      gather_pipe4(H, half, col4, headsel, s, p0, p1, rem, acc);
    }
  }

  // epilogue: per-lane inv (own head), head-mean via xor16, bias, relu
  float il = headsel ? inv1 : inv0;
  float4 v = make_float4(acc.x * il, acc.y * il, acc.z * il, acc.w * il);
  float4 w;
  w.x = __shfl_xor(v.x, 16, 64);
  w.y = __shfl_xor(v.y, 16, 64);
  w.z = __shfl_xor(v.z, 16, 64);
  w.w = __shfl_xor(v.w, 16, 64);
  if (headsel == 0 && live) {
    int c = (l32 & 15) * 4;
    float4 b4 = *(const float4*)(bias + c);
    float4 r;
    r.x = fmaxf(0.5f * (v.x + w.x) + b4.x, 0.f);
    r.y = fmaxf(0.5f * (v.y + w.y) + b4.y, 0.f);
    r.z = fmaxf(0.5f * (v.z + w.z) + b4.z, 0.f);
    r.w = fmaxf(0.5f * (v.w + w.w) + b4.w, 0.f);
    if (POOL) {
      float4 l4 = *(const float4*)(lw + c);
      float pv = r.x * l4.x + r.y * l4.y + r.z * l4.z + r.w * l4.w;
      pv += __shfl_xor(pv, 1, 64);
      pv += __shfl_xor(pv, 2, 64);
      pv += __shfl_xor(pv, 4, 64);
      pv += __shfl_xor(pv, 8, 64);
      if ((l32 & 15) == 0) pvn[dst] = pv;
    } else {
      *(float4*)(out + (size_t)dst * 64 + c) = r;
    }
  }
}

__device__ __forceinline__ int lower_bound(const int* __restrict__ a, int n, int key) {
  int lo = 0, hi = n;
  while (lo < hi) {
    int mid = (lo + hi) >> 1;
    if (a[mid] < key) lo = mid + 1; else hi = mid;
  }
  return lo;
}

// per graph: boundaries via binary search in sorted batch, mean of pvn + lb
__global__ void finalize_kernel(const float* __restrict__ pvn,
                                const int* __restrict__ batch,
                                const float* __restrict__ lb,
                                float* __restrict__ out, int N, int G) {
  int g = blockIdx.x * blockDim.x + threadIdx.x;
  if (g >= G) return;
  int lo = lower_bound(batch, N, g);
  int hi = lower_bound(batch, N, g + 1);
  float s = 0.f;
  for (int i = lo; i < hi; ++i) s += pvn[i];
  out[g] = s / fmaxf((float)(hi - lo), 1.f) + lb[0];
}

extern "C" void kernel_launch(void* const* d_in, const int* in_sizes, int n_in,
                              void* d_out, int out_size, void* d_ws, size_t ws_size,
                              hipStream_t stream) {
  const float* x   = (const float*)d_in[0];
  const int* ei    = (const int*)d_in[1];
  const int* batch = (const int*)d_in[2];
  const float* W1  = (const float*)d_in[3];
  const float* as1 = (const float*)d_in[4];
  const float* ad1 = (const float*)d_in[5];
  const float* b1  = (const float*)d_in[6];
  const float* W2  = (const float*)d_in[7];
  const float* as2 = (const float*)d_in[8];
  const float* ad2 = (const float*)d_in[9];
  const float* b2  = (const float*)d_in[10];
  const float* W3  = (const float*)d_in[11];
  const float* as3 = (const float*)d_in[12];
  const float* ad3 = (const float*)d_in[13];
  const float* b3  = (const float*)d_in[14];
  const float* lw  = (const float*)d_in[15];
  const float* lb  = (const float*)d_in[16];
  float* out = (float*)d_out;

  const int N = in_sizes[0] / 128;   // 50000
  const int E = in_sizes[1] / 2;     // 800000
  const int ET = N + E;              // with self loops
  const int G = out_size;            // 2500
  const int NB = (N + 255) / 256;    // scan blocks (196 <= 256)

  char* p = (char*)d_ws;
  auto take = [&](size_t bytes) {
    char* r = p;
    p += (bytes + 255) & ~(size_t)255;
    return r;
  };
  int* deg      = (int*)take((size_t)N * 4);
  int* row_ptr  = (int*)take((size_t)(N + 1) * 4);
  int* rank     = (int*)take((size_t)E * 4);
  int* btot     = (int*)take((size_t)NB * 4);
  int* csr      = (int*)take((size_t)ET * 4);
  float* H      = (float*)take((size_t)N * 128 * 4);
  float* a_src  = (float*)take((size_t)N * 2 * 4);
  float* a_dst  = (float*)take((size_t)N * 2 * 4);
  float* bufA   = (float*)take((size_t)N * 64 * 4);
  float* bufB   = (float*)take((size_t)N * 64 * 4);
  float* pvn    = (float*)take((size_t)N * 4);
  (void)ws_size; (void)n_in;

  // ---- CSR build (dst-grouped, with self loops) ----
  init_kernel<<<(N + 255) / 256, 256, 0, stream>>>(deg, N);
  count_rank<<<(E + 1023) / 1024, 256, 0, stream>>>(ei, deg, rank, E);
  scan_blocks<<<NB, 256, 0, stream>>>(deg, row_ptr, btot, N);
  scan_totals<<<1, 256, 0, stream>>>(btot, NB);
  scan_add<<<NB, 256, 0, stream>>>(row_ptr, csr, btot, N, ET);
  place_kernel<<<(E + 1023) / 1024, 256, 0, stream>>>(ei, rank, row_ptr, csr, E);

  const dim3 gblk((N + 63) / 64, 2);
  const int ablk = (N + 7) / 8;   // 8 dsts per block (2 per wave)

  // ---- layer 1 (K=128) ----
  gemm_att<128><<<gblk, 256, 0, stream>>>(x, W1, as1, ad1, H, a_src, a_dst, N);
  aggregate_fused<0><<<ablk, 256, 0, stream>>>(H, a_src, a_dst, b1, row_ptr, csr,
                                               bufA, lw, pvn, N);
  // ---- layer 2 (K=64) ----
  gemm_att<64><<<gblk, 256, 0, stream>>>(bufA, W2, as2, ad2, H, a_src, a_dst, N);
  aggregate_fused<0><<<ablk, 256, 0, stream>>>(H, a_src, a_dst, b2, row_ptr, csr,
                                               bufB, lw, pvn, N);
  // ---- layer 3 (K=64) + fused pool ----
  gemm_att<64><<<gblk, 256, 0, stream>>>(bufB, W3, as3, ad3, H, a_src, a_dst, N);
  aggregate_fused<1><<<ablk, 256, 0, stream>>>(H, a_src, a_dst, b3, row_ptr, csr,
                                               bufA, lw, pvn, N);

  // ---- finalize: per-graph mean + linear ----
  finalize_kernel<<<(G + 255) / 256, 256, 0, stream>>>(pvn, batch, lb, out, N, G);
}